// Round 1
// baseline (112.558 us; speedup 1.0000x reference)
//
#include <hip/hip_runtime.h>

// MountainCar batched rollout: B=8192 envs, 500 sequential steps of a
// 2->64->1 MLP policy + dynamics. Compute-bound (VALU), memory negligible.
//
// Layout: 8 lanes per env (KL=8), each lane owns 8 hidden units with weights
// held in VGPRs. Layer-2 dot product reduced across the 8 lanes with DPP adds
// (no LDS, no ds_swizzle). State (p,v,u,r) replicated across the env's lanes.

constexpr int B = 8192;
constexpr int L = 64;
constexpr int MAX_STEPS = 500;
constexpr float GOAL_P = 0.5f;
constexpr float MIN_P  = -1.2f;
constexpr float MIN_V  = -0.07f;
constexpr float MAX_V  = 0.07f;
constexpr float MIN_ACC = -1.2f;
constexpr float MAX_ACC = 1.2f;

constexpr int KL  = 8;        // lanes per env
constexpr int UPL = L / KL;   // hidden units per lane = 8

// x + value-from-lane(ctrl) ; CTRL must be an ICE -> template param
template<int CTRL>
__device__ __forceinline__ float dpp_add(float x) {
  int y = __builtin_amdgcn_update_dpp(0, __float_as_int(x), CTRL, 0xf, 0xf, true);
  return x + __int_as_float(y);
}

// tanh(x) = sign(x) * (1 - 2/(exp(2|x|)+1)), exp via hardware exp2.
// Saturates correctly for large |x| (exp2 -> inf -> t -> 1).
__device__ __forceinline__ float fast_tanh(float x) {
  float a = fabsf(x);
  float e = __builtin_amdgcn_exp2f(a * 2.8853900817779268f); // 2*log2(e)
  float t = 1.0f - 2.0f * __builtin_amdgcn_rcpf(e + 1.0f);
  return copysignf(t, x);
}

__global__ __launch_bounds__(256) void mc_kernel(
    const float* __restrict__ x,  const float* __restrict__ w1,
    const float* __restrict__ b1, const float* __restrict__ w2,
    const float* __restrict__ b2, float* __restrict__ out)
{
  int tid = blockIdx.x * blockDim.x + threadIdx.x;
  int env = tid >> 3;   // env index
  int sub = tid & 7;    // lane-within-env

  // Weights for hidden units j = sub*UPL + i, resident in VGPRs for the
  // whole rollout (32 regs/lane).
  float w1a[UPL], w1b[UPL], b1r[UPL], w2r[UPL];
  const int j0 = sub * UPL;
#pragma unroll
  for (int i = 0; i < UPL; ++i) {
    w1a[i] = w1[j0 + i];        // w1[0][j]
    w1b[i] = w1[L + j0 + i];    // w1[1][j]
    b1r[i] = b1[j0 + i];
    w2r[i] = w2[j0 + i];        // w2[j][0]
  }
  const float b2v = b2[0];

  float4 st = reinterpret_cast<const float4*>(x)[env];
  float p = st.x, v = st.y, u = st.z, r = st.w;

  for (int stp = 0; stp < MAX_STEPS; ++stp) {
    bool active = (p <= GOAL_P);
    if (!__any(active)) break;          // whole wave's envs done

    float p1 = fmaxf(p, MIN_P);                 // where(hit, MIN_P, p)
    float v1 = (p <= MIN_P) ? 0.0f : v;         // where(hit, 0, v)

    // Layer 1 (relu) + partial layer-2 dot for this lane's 8 units.
    float s = 0.0f;
#pragma unroll
    for (int i = 0; i < UPL; ++i) {
      float h = fmaf(v1, w1b[i], fmaf(p1, w1a[i], b1r[i]));
      h = fmaxf(h, 0.0f);
      s = fmaf(h, w2r[i], s);
    }
    // Reduce across the env's 8 lanes; all lanes end with the full sum.
    s = dpp_add<0xB1>(s);    // quad_perm [1,0,3,2]  : + lane^1
    s = dpp_add<0x4E>(s);    // quad_perm [2,3,0,1]  : + lane^2
    s = dpp_add<0x141>(s);   // row_half_mirror (^7) : + other quad's sum

    float u1 = fast_tanh(s + b2v);
    u1 = fminf(fmaxf(u1, MIN_ACC), MAX_ACC);

    float r1 = fmaf(-0.1f * u1, u1, r);

    // cos(3*p1): v_cos takes revolutions -> multiply by 3/(2*pi).
    float c = __builtin_amdgcn_cosf(p1 * 0.47746482927568601f);

    float v2 = fmaf(-0.0025f, c, fmaf(0.0015f, u1, v1));
    v2 = fminf(fmaxf(v2, MIN_V), MAX_V);
    float p2 = p1 + v2;

    if (active) { p = p2; v = v2; u = u1; r = r1; }
  }

  if (sub == 0) {
    float rout = (p <= GOAL_P) ? r : r + 100.0f;
    reinterpret_cast<float4*>(out)[env] = make_float4(p, v, u, rout);
  }
}

extern "C" void kernel_launch(void* const* d_in, const int* in_sizes, int n_in,
                              void* d_out, int out_size, void* d_ws, size_t ws_size,
                              hipStream_t stream) {
  const float* x  = (const float*)d_in[0];
  const float* w1 = (const float*)d_in[1];
  const float* b1 = (const float*)d_in[2];
  const float* w2 = (const float*)d_in[3];
  const float* b2 = (const float*)d_in[4];
  float* out = (float*)d_out;

  constexpr int threads = B * KL;  // 65536 -> 1024 waves -> 1 wave/SIMD chip-wide
  mc_kernel<<<threads / 256, 256, 0, stream>>>(x, w1, b1, w2, b2, out);
}

// Round 2
// 92.684 us; speedup vs baseline: 1.2144x; 1.2144x over previous
//
#include <hip/hip_runtime.h>

// MountainCar batched rollout: B=8192 envs, 500 sequential steps of a
// 2->64->1 MLP policy + dynamics. Latency-bound VALU problem.
//
// Round 2: KL=16 lanes/env (4 hidden units per lane) -> 2048 waves =
// 2 waves/SIMD chip-wide, doubling latency hiding (round 1 was 1 wave/SIMD,
// VALUBusy 45%). Weights in VGPRs; 16-lane reduction via 4 DPP adds.
// tanh arg pre-scaled into w2/b2 (saves a dependent mul/step); u1 clip
// dropped (tanh output strictly inside [-1.2,1.2] -> exact identity).

constexpr int B = 8192;
constexpr int L = 64;
constexpr int MAX_STEPS = 500;
constexpr float GOAL_P = 0.5f;
constexpr float MIN_P  = -1.2f;
constexpr float MIN_V  = -0.07f;
constexpr float MAX_V  = 0.07f;

constexpr int KL  = 16;       // lanes per env
constexpr int UPL = L / KL;   // hidden units per lane = 4

template<int CTRL>
__device__ __forceinline__ float dpp_add(float x) {
  int y = __builtin_amdgcn_update_dpp(0, __float_as_int(x), CTRL, 0xf, 0xf, true);
  return x + __int_as_float(y);
}

__global__ __launch_bounds__(256) void mc_kernel(
    const float* __restrict__ x,  const float* __restrict__ w1,
    const float* __restrict__ b1, const float* __restrict__ w2,
    const float* __restrict__ b2, float* __restrict__ out)
{
  int tid = blockIdx.x * blockDim.x + threadIdx.x;
  int env = tid >> 4;   // env index
  int sub = tid & 15;   // lane-within-env

  // 2*log2(e): fold tanh's argument scaling into the layer-2 weights so the
  // per-step dependent chain loses one multiply. sign(s) unchanged (scale>0).
  constexpr float TS = 2.8853900817779268f;

  float w1a[UPL], w1b[UPL], b1r[UPL], w2r[UPL];
  const int j0 = sub * UPL;
#pragma unroll
  for (int i = 0; i < UPL; ++i) {
    w1a[i] = w1[j0 + i];          // w1[0][j]
    w1b[i] = w1[L + j0 + i];      // w1[1][j]
    b1r[i] = b1[j0 + i];
    w2r[i] = w2[j0 + i] * TS;     // w2[j][0], pre-scaled
  }
  const float b2v = b2[0] * TS;

  float4 st = reinterpret_cast<const float4*>(x)[env];
  float p = st.x, v = st.y, u = st.z, r = st.w;

  for (int stp = 0; stp < MAX_STEPS; ++stp) {
    bool active = (p <= GOAL_P);
    if (!__any(active)) break;

    float p1 = fmaxf(p, MIN_P);
    float v1 = (p <= MIN_P) ? 0.0f : v;

    // Layer 1 (relu) + partial layer-2 dot: two accumulation chains.
    float h0 = fmaxf(fmaf(v1, w1b[0], fmaf(p1, w1a[0], b1r[0])), 0.0f);
    float h1 = fmaxf(fmaf(v1, w1b[1], fmaf(p1, w1a[1], b1r[1])), 0.0f);
    float h2 = fmaxf(fmaf(v1, w1b[2], fmaf(p1, w1a[2], b1r[2])), 0.0f);
    float h3 = fmaxf(fmaf(v1, w1b[3], fmaf(p1, w1a[3], b1r[3])), 0.0f);
    float s0 = fmaf(h2, w2r[2], h0 * w2r[0]);
    float s1 = fmaf(h3, w2r[3], h1 * w2r[1]);
    float s  = s0 + s1;

    // Reduce across the env's 16 lanes (one DPP row); all lanes get the sum.
    s = dpp_add<0xB1>(s);     // quad_perm [1,0,3,2] : + lane^1
    s = dpp_add<0x4E>(s);     // quad_perm [2,3,0,1] : + lane^2
    s = dpp_add<0x141>(s);    // row_half_mirror    : + lane^(4..7)
    s = dpp_add<0x140>(s);    // row_mirror         : + lane^(8..15)

    // tanh: arg already scaled by 2*log2(e). tanh in (-1,1) -> clip is a no-op.
    float a  = fabsf(s + b2v);
    float e  = __builtin_amdgcn_exp2f(a);
    float t  = fmaf(-2.0f, __builtin_amdgcn_rcpf(e + 1.0f), 1.0f);
    float u1 = copysignf(t, s + b2v);

    float r1 = fmaf(-0.1f * u1, u1, r);

    // cos(3*p1): v_cos takes revolutions -> multiply by 3/(2*pi).
    float c = __builtin_amdgcn_cosf(p1 * 0.47746482927568601f);

    float v2 = fmaf(-0.0025f, c, fmaf(0.0015f, u1, v1));
    v2 = fminf(fmaxf(v2, MIN_V), MAX_V);
    float p2 = p1 + v2;

    if (active) { p = p2; v = v2; u = u1; r = r1; }
  }

  if (sub == 0) {
    float rout = (p <= GOAL_P) ? r : r + 100.0f;
    reinterpret_cast<float4*>(out)[env] = make_float4(p, v, u, rout);
  }
}

extern "C" void kernel_launch(void* const* d_in, const int* in_sizes, int n_in,
                              void* d_out, int out_size, void* d_ws, size_t ws_size,
                              hipStream_t stream) {
  const float* x  = (const float*)d_in[0];
  const float* w1 = (const float*)d_in[1];
  const float* b1 = (const float*)d_in[2];
  const float* w2 = (const float*)d_in[3];
  const float* b2 = (const float*)d_in[4];
  float* out = (float*)d_out;

  constexpr int threads = B * KL;  // 131072 -> 2048 waves -> 2 waves/SIMD
  mc_kernel<<<threads / 256, 256, 0, stream>>>(x, w1, b1, w2, b2, out);
}

// Round 4
// 86.279 us; speedup vs baseline: 1.3046x; 1.0742x over previous
//
#include <hip/hip_runtime.h>

// MountainCar batched rollout: B=8192 envs, 500 sequential steps of a
// 2->64->1 MLP policy + dynamics. VALU issue-bound; memory ~0.
//
// Round 4 = round 2's proven skeleton (intrinsic DPP butterfly, cndmask
// state merges) + safe instruction diets:
//  - sign-free tanh: 1 - 2*rcp(exp2(k*x)+1)  (exact both saturations)
//  - b2 folded into lane-0's layer-2 seed (butterfly distributes it)
//  - reward scale deferred: racc += u^2 in-loop, r = r0 - 0.1*racc at end
// Round 3's raw inline-asm v_add_f32_dpp FAILED: back-to-back DPP reads of
// a just-written VGPR need 2 wait states (GFX9 DPP hazard); inline asm
// bypasses the compiler's hazard recognizer. Intrinsics restore correctness.

constexpr int B = 8192;
constexpr int L = 64;
constexpr int MAX_STEPS = 500;
constexpr float GOAL_P = 0.5f;
constexpr float MIN_P  = -1.2f;
constexpr float MIN_V  = -0.07f;
constexpr float MAX_V  = 0.07f;

constexpr int KL  = 16;       // lanes per env
constexpr int UPL = L / KL;   // hidden units per lane = 4

// x + x_from_lane(CTRL); compiler inserts DPP hazard nops / may fuse to
// v_add_f32_dpp (old=0 is the add identity, bound_ctrl=true).
template<int CTRL>
__device__ __forceinline__ float dpp_add(float x) {
  int y = __builtin_amdgcn_update_dpp(0, __float_as_int(x), CTRL, 0xf, 0xf, true);
  return x + __int_as_float(y);
}

__global__ __launch_bounds__(256) void mc_kernel(
    const float* __restrict__ x,  const float* __restrict__ w1,
    const float* __restrict__ b1, const float* __restrict__ w2,
    const float* __restrict__ b2, float* __restrict__ out)
{
  int tid = blockIdx.x * blockDim.x + threadIdx.x;
  int env = tid >> 4;   // env index
  int sub = tid & 15;   // lane-within-env

  // 2*log2(e): fold tanh's argument scaling into w2/b2 (positive scale,
  // sign of the logit unchanged).
  constexpr float TS = 2.8853900817779268f;

  float w1a[UPL], w1b[UPL], b1r[UPL], w2r[UPL];
  const int j0 = sub * UPL;
#pragma unroll
  for (int i = 0; i < UPL; ++i) {
    w1a[i] = w1[j0 + i];          // w1[0][j]
    w1b[i] = w1[L + j0 + i];      // w1[1][j]
    b1r[i] = b1[j0 + i];
    w2r[i] = w2[j0 + i] * TS;     // w2[j][0], pre-scaled
  }
  // b2 seeded into lane 0's partial sum; the butterfly distributes it so
  // every lane's total contains exactly one b2.
  const float b2seed = (sub == 0) ? b2[0] * TS : 0.0f;

  float4 st = reinterpret_cast<const float4*>(x)[env];
  const float r0 = st.w;
  float p = st.x, v = st.y, u = st.z;
  float racc = 0.0f;   // sum of u^2 over active steps

  for (int stp = 0; stp < MAX_STEPS; ++stp) {
    bool active = (p <= GOAL_P);
    if (!__any(active)) break;

    float p1 = fmaxf(p, MIN_P);
    float v1 = (p <= MIN_P) ? 0.0f : v;

    // cos(3*p1): v_cos takes revolutions; independent of the MLP chain.
    float c = __builtin_amdgcn_cosf(p1 * 0.47746482927568601f);

    // Layer 1 (relu) + layer-2 partial dot, seeded with b2 on lane 0.
    float h0 = fmaxf(fmaf(v1, w1b[0], fmaf(p1, w1a[0], b1r[0])), 0.0f);
    float h1 = fmaxf(fmaf(v1, w1b[1], fmaf(p1, w1a[1], b1r[1])), 0.0f);
    float h2 = fmaxf(fmaf(v1, w1b[2], fmaf(p1, w1a[2], b1r[2])), 0.0f);
    float h3 = fmaxf(fmaf(v1, w1b[3], fmaf(p1, w1a[3], b1r[3])), 0.0f);
    float s = b2seed;
    s = fmaf(h0, w2r[0], s);
    s = fmaf(h1, w2r[1], s);
    s = fmaf(h2, w2r[2], s);
    s = fmaf(h3, w2r[3], s);

    // 16-lane butterfly; every lane ends with the full pre-scaled logit.
    s = dpp_add<0xB1>(s);     // quad_perm [1,0,3,2] : + lane^1
    s = dpp_add<0x4E>(s);     // quad_perm [2,3,0,1] : + lane^2
    s = dpp_add<0x141>(s);    // row_half_mirror    : + lane^(4..7)
    s = dpp_add<0x140>(s);    // row_mirror         : + lane^(8..15)

    // tanh, sign-free: 1 - 2/(exp2(s)+1); exact at both saturations.
    float e  = __builtin_amdgcn_exp2f(s);
    float u1 = fmaf(-2.0f, __builtin_amdgcn_rcpf(e + 1.0f), 1.0f);

    float v2 = fmaf(-0.0025f, c, fmaf(0.0015f, u1, v1));
    v2 = fminf(fmaxf(v2, MIN_V), MAX_V);
    float p2 = p1 + v2;

    if (active) {
      p = p2; v = v2; u = u1;
      racc = fmaf(u1, u1, racc);
    }
  }

  if (sub == 0) {
    float rbase = fmaf(-0.1f, racc, r0);
    float rout  = (p <= GOAL_P) ? rbase : rbase + 100.0f;
    reinterpret_cast<float4*>(out)[env] = make_float4(p, v, u, rout);
  }
}

extern "C" void kernel_launch(void* const* d_in, const int* in_sizes, int n_in,
                              void* d_out, int out_size, void* d_ws, size_t ws_size,
                              hipStream_t stream) {
  const float* x  = (const float*)d_in[0];
  const float* w1 = (const float*)d_in[1];
  const float* b1 = (const float*)d_in[2];
  const float* w2 = (const float*)d_in[3];
  const float* b2 = (const float*)d_in[4];
  float* out = (float*)d_out;

  constexpr int threads = B * KL;  // 131072 -> 2048 waves -> 2 waves/SIMD
  mc_kernel<<<threads / 256, 256, 0, stream>>>(x, w1, b1, w2, b2, out);
}